// Round 7
// baseline (460.588 us; speedup 1.0000x reference)
//
#include <hip/hip_runtime.h>
#include <math.h>

#define Bn 4096
#define Tn 512
#define Vn 57
#define En 20
#define Hn 128
#define On 18
#define ROWS 16          // batch rows per block (= MFMA N)
#define NTHR 64          // ONE wave: whole recurrence in-register, zero barriers
#define NBLK (Bn / ROWS) // 256 blocks -> 1 wave per CU
#define XWSTR 132        // xw table row stride (floats), 16B-aligned rows
#define XBSTR 516        // id byte-row stride: word bank = (n + t/4) % 32, conflict-free
#define HFSTR 132        // final-h fp32 row stride
#define ASCALE 2.8853900817779268f   // 2*log2(e): folds tanh's 2x and log2e mul in

typedef _Float16 half8  __attribute__((ext_vector_type(8)));
typedef __fp16   fp16x2 __attribute__((ext_vector_type(2)));   // cvt_pkrtz native type
typedef float    floatx4 __attribute__((ext_vector_type(4)));

// acc is pre-scaled by 2*log2e: tanh(x) = 1 - 2/(1+2^(2x*log2e))
__device__ __forceinline__ float tanh_scaled(float z) {
    float e = __builtin_amdgcn_exp2f(z);          // v_exp_f32
    float r = __builtin_amdgcn_rcpf(e + 1.0f);    // v_rcp_f32
    return fmaf(-2.0f, r, 1.0f);
}

__device__ __forceinline__ unsigned pk_u32(fp16x2 v) {
    union { fp16x2 h; unsigned u; } c; c.h = v; return c.u;
}

__device__ __forceinline__ half8 as_half8(uint4 v) {
    union { uint4 u; half8 h; } c; c.u = v; return c.h;
}

// (64, 1): 1 wave/block -> VGPR cap 512; demand ~270 (A 128 + XW 32 + bF 16 +
// hreg 32 + acc 32 + misc). All register arrays fully-unrolled static indices
// (R4 lesson: runtime-indexed ext_vector arrays go to scratch).
__launch_bounds__(NTHR, 1)
__global__ void rnn_mfma_kernel(const int* __restrict__ x,
                                const int* __restrict__ xlen,
                                const float* __restrict__ emb,
                                const float* __restrict__ W_ih,
                                const float* __restrict__ W_hh,
                                const float* __restrict__ b_ih,
                                const float* __restrict__ b_hh,
                                const float* __restrict__ W_out,
                                const float* __restrict__ b_out,
                                float* __restrict__ out)
{
    // No h exchange buffers: state lives in registers as 4 B-fragments.
    // LDS only holds the XW table, token ids, and epilogue staging.
    __shared__ __align__(16) float sXW[Vn * XWSTR];   // xw[id][f] = (W_ih.emb[id]+b)*ASCALE
    __shared__ __align__(16) float sHf[ROWS * HFSTR];
    __shared__ __align__(16) unsigned char sXb[ROWS * XBSTR];  // token ids as bytes
    __shared__ float sLogit[ROWS][On];
    __shared__ float sMLS[ROWS];

    const int tid  = threadIdx.x;    // == lane
    const int blk  = blockIdx.x;
    const int row0 = blk * ROWS;
    const int n    = tid & 15;       // batch col (B/C) AND A fragment row m
    const int q    = tid >> 4;       // quad

    // ---- xw lookup table (f32, exact). Lane-resident W rows: lane j builds
    // features j and j+64 for all 57 vocab entries (emb reads broadcast).
    {
        float wA[En], wB[En];
        #pragma unroll
        for (int e = 0; e < En; ++e) {
            wA[e] = W_ih[tid * En + e];
            wB[e] = W_ih[(tid + 64) * En + e];
        }
        const float bA = b_ih[tid] + b_hh[tid];
        const float bB = b_ih[tid + 64] + b_hh[tid + 64];
        for (int vo = 0; vo < Vn; ++vo) {
            float aA = bA, aB = bB;
            #pragma unroll
            for (int e = 0; e < En; ++e) {
                float ev = emb[vo * En + e];
                aA = fmaf(ev, wA[e], aA);
                aB = fmaf(ev, wB[e], aB);
            }
            sXW[vo * XWSTR + tid]      = aA * ASCALE;
            sXW[vo * XWSTR + tid + 64] = aB * ASCALE;
        }
    }
    // ---- stage vocab ids as bytes (vocab=57 < 256); int4 load, uchar4 store
    for (int idx = tid * 4; idx < ROWS * Tn; idx += NTHR * 4) {
        int4 v = *(const int4*)&x[row0 * Tn + idx];
        int r = idx >> 9, t = idx & 511;
        uchar4 bb;
        bb.x = (unsigned char)v.x; bb.y = (unsigned char)v.y;
        bb.z = (unsigned char)v.z; bb.w = (unsigned char)v.w;
        *(uchar4*)&sXb[r * XBSTR + t] = bb;
    }

    // ---- A operand (static, 128 VGPRs): 8 tiles x 4 K-chunks. PERMUTED row map
    // per tile tau: A row m loads weight row
    //   F(tau,m) = 32*(tau>>1) + 8*(m>>2) + 4*(tau&1) + (m&3)
    // so C output reg i of tile tau at lane (q,n) == h feature
    //   F = 32*(tau>>1) + 8q + 4*(tau&1) + i.
    // Tile pair (2c,2c+1) then packs (cvt_pkrtz) into EXACTLY B-fragment c
    // (k = 32c+8q+j) -- the recurrent state never leaves the register file.
    // Pre-scaled by 2*log2e (tanh input fusion).
    half8 Ah[8][4];
    #pragma unroll
    for (int tau = 0; tau < 8; ++tau) {
        const int f = 32 * (tau >> 1) + 8 * (n >> 2) + 4 * (tau & 1) + (n & 3);
        #pragma unroll
        for (int kc = 0; kc < 4; ++kc) {
            const float* p = &W_hh[f * Hn + kc * 32 + q * 8];
            #pragma unroll
            for (int i = 0; i < 8; ++i)
                Ah[tau][kc][i] = (_Float16)(p[i] * ASCALE);
        }
    }
    __syncthreads();   // single wave: cheap; orders LDS writes before reads

    const int Lmax  = xlen[row0];        // sorted descending -> block trip count
    const int len_n = xlen[row0 + n];    // per batch-col freeze point

    // ---- xw pipeline: lane (q,n) needs xw[id(t)][F(tau,4q+i)] (float4 per tile)
    // as accumulator init. Prefetched one step ahead; gather ~2-way conflicts
    // (free per m136): window bank = (4id + 8q + 4(tau&1)) % 32.
    float4 XWc[8];
    int    idN;
    {
        int id0 = sXb[n * XBSTR];
        #pragma unroll
        for (int tau = 0; tau < 8; ++tau)
            XWc[tau] = *(const float4*)&sXW[id0 * XWSTR + 32 * (tau >> 1) + 8 * q + 4 * (tau & 1)];
        idN = sXb[n * XBSTR + (Lmax > 1 ? 1 : 0)];
    }

    float hreg[32];                       // fp32 shadow of this lane's 32 h values
    #pragma unroll
    for (int i = 0; i < 32; ++i) hreg[i] = 0.f;
    uint4 bF[4];                          // h state as packed B-fragments (h0 = 0)
    #pragma unroll
    for (int c = 0; c < 4; ++c) bF[c] = make_uint4(0u, 0u, 0u, 0u);

    // one step, zero barriers: 32 MFMAs (8 tiles x 4 chunks, chain depth 4,
    // init = prefetched f32 xw), prefetch xw/id for t+1 right after chunk 0,
    // tanh+freeze on the fp32 shadow, repack into bF. Next step's chunk-0
    // MFMAs only need bF[0] (tiles 0,1) -> compiler can overlap across steps.
    #define RNN_STEP(t)                                                           \
    {                                                                             \
        half8 b0 = as_half8(bF[0]), b1 = as_half8(bF[1]);                         \
        half8 b2 = as_half8(bF[2]), b3 = as_half8(bF[3]);                         \
        floatx4 a[8];                                                             \
        _Pragma("unroll")                                                         \
        for (int tau = 0; tau < 8; ++tau) {                                       \
            floatx4 ci = {XWc[tau].x, XWc[tau].y, XWc[tau].z, XWc[tau].w};        \
            a[tau] = __builtin_amdgcn_mfma_f32_16x16x32_f16(Ah[tau][0], b0, ci, 0, 0, 0); \
        }                                                                         \
        _Pragma("unroll")                                                         \
        for (int tau = 0; tau < 8; ++tau)                                         \
            XWc[tau] = *(const float4*)&sXW[idN * XWSTR + 32 * (tau >> 1) + 8 * q + 4 * (tau & 1)]; \
        int tn = (t) + 2;                                                         \
        int idN2 = sXb[n * XBSTR + (tn < Lmax ? tn : Lmax - 1)];                  \
        _Pragma("unroll")                                                         \
        for (int tau = 0; tau < 8; ++tau)                                         \
            a[tau] = __builtin_amdgcn_mfma_f32_16x16x32_f16(Ah[tau][1], b1, a[tau], 0, 0, 0); \
        _Pragma("unroll")                                                         \
        for (int tau = 0; tau < 8; ++tau)                                         \
            a[tau] = __builtin_amdgcn_mfma_f32_16x16x32_f16(Ah[tau][2], b2, a[tau], 0, 0, 0); \
        _Pragma("unroll")                                                         \
        for (int tau = 0; tau < 8; ++tau)                                         \
            a[tau] = __builtin_amdgcn_mfma_f32_16x16x32_f16(Ah[tau][3], b3, a[tau], 0, 0, 0); \
        const bool upd = ((t) < len_n);                                           \
        _Pragma("unroll")                                                         \
        for (int tau = 0; tau < 8; ++tau) {                                       \
            _Pragma("unroll")                                                     \
            for (int i = 0; i < 4; ++i) {                                         \
                float v = tanh_scaled(a[tau][i]);                                 \
                hreg[4 * tau + i] = upd ? v : hreg[4 * tau + i];                  \
            }                                                                     \
        }                                                                         \
        _Pragma("unroll")                                                         \
        for (int c = 0; c < 4; ++c) {                                             \
            uint4 pk;                                                             \
            pk.x = pk_u32(__builtin_amdgcn_cvt_pkrtz(hreg[8 * c + 0], hreg[8 * c + 1])); \
            pk.y = pk_u32(__builtin_amdgcn_cvt_pkrtz(hreg[8 * c + 2], hreg[8 * c + 3])); \
            pk.z = pk_u32(__builtin_amdgcn_cvt_pkrtz(hreg[8 * c + 4], hreg[8 * c + 5])); \
            pk.w = pk_u32(__builtin_amdgcn_cvt_pkrtz(hreg[8 * c + 6], hreg[8 * c + 7])); \
            bF[c] = pk;                                                           \
        }                                                                         \
        idN = idN2;                                                               \
    }

    int t = 0;
    for (; t + 2 <= Lmax; t += 2) {
        RNN_STEP(t);
        RNN_STEP(t + 1);
    }
    if (t < Lmax) {
        RNN_STEP(t);
    }
    #undef RNN_STEP

    // ---- publish final fp32 h: lane (q,n) tile tau reg i holds feature
    // 32*(tau>>1) + 8q + 4*(tau&1) + i of batch col n.
    #pragma unroll
    for (int tau = 0; tau < 8; ++tau) {
        float4 f0;
        f0.x = hreg[4 * tau + 0]; f0.y = hreg[4 * tau + 1];
        f0.z = hreg[4 * tau + 2]; f0.w = hreg[4 * tau + 3];
        *(float4*)&sHf[n * HFSTR + 32 * (tau >> 1) + 8 * q + 4 * (tau & 1)] = f0;
    }
    __syncthreads();

    // ---- epilogue: logits = relu(h) @ W_out^T + b_out, then log_softmax
    for (int it = tid; it < ROWS * On; it += NTHR) {
        int r = it / On, c = it % On;
        float acc = b_out[c];
        for (int k = 0; k < Hn; ++k) {
            float hv = sHf[r * HFSTR + k];
            hv = hv > 0.0f ? hv : 0.0f;
            acc = fmaf(hv, W_out[c * Hn + k], acc);
        }
        sLogit[r][c] = acc;
    }
    __syncthreads();

    if (tid < ROWS) {
        float m = -INFINITY;
        #pragma unroll
        for (int c = 0; c < On; ++c) m = fmaxf(m, sLogit[tid][c]);
        float s = 0.0f;
        #pragma unroll
        for (int c = 0; c < On; ++c) s += __expf(sLogit[tid][c] - m);
        sMLS[tid] = m + __logf(s);
    }
    __syncthreads();

    for (int it = tid; it < ROWS * On; it += NTHR) {
        int r = it / On, c = it % On;
        out[(row0 + r) * On + c] = sLogit[r][c] - sMLS[r];
    }
}

extern "C" void kernel_launch(void* const* d_in, const int* in_sizes, int n_in,
                              void* d_out, int out_size, void* d_ws, size_t ws_size,
                              hipStream_t stream) {
    const int*   x     = (const int*)d_in[0];
    const int*   xlen  = (const int*)d_in[1];
    const float* emb   = (const float*)d_in[2];
    const float* W_ih  = (const float*)d_in[3];
    const float* W_hh  = (const float*)d_in[4];
    const float* b_ih  = (const float*)d_in[5];
    const float* b_hh  = (const float*)d_in[6];
    const float* W_out = (const float*)d_in[7];
    const float* b_out = (const float*)d_in[8];
    float*       out   = (float*)d_out;

    rnn_mfma_kernel<<<NBLK, NTHR, 0, stream>>>(x, xlen, emb, W_ih, W_hh,
                                               b_ih, b_hh, W_out, b_out, out);
}

// Round 9
// 273.676 us; speedup vs baseline: 1.6830x; 1.6830x over previous
//
#include <hip/hip_runtime.h>
#include <math.h>

#define Bn 4096
#define Tn 512
#define Vn 57
#define En 20
#define Hn 128
#define On 18
#define ROWS 16          // batch rows per block (= MFMA N)
#define NTHR 512         // 8 waves = 2/SIMD: spreads fixed per-step trans/MFMA work
#define NBLK (Bn / ROWS) // 256 blocks -> 1 per CU (LDS pad keeps it that way)
#define XWSTR 132        // xw table row stride (floats), 16B-aligned rows
#define XBSTR 516        // id byte-row stride: word bank = (n + t/4) % 32, conflict-free
#define HFSTR 132        // final-h fp32 row stride
#define ASCALE 2.8853900817779268f   // 2*log2(e): folds tanh's 2x and log2e mul in

typedef _Float16 half8  __attribute__((ext_vector_type(8)));
typedef __fp16   fp16x2 __attribute__((ext_vector_type(2)));   // cvt_pkrtz native type
typedef float    floatx4 __attribute__((ext_vector_type(4)));

// acc is pre-scaled by 2*log2e: tanh(x) = 1 - 2/(1+2^(2x*log2e))
__device__ __forceinline__ float tanh_scaled(float z) {
    float e = __builtin_amdgcn_exp2f(z);          // v_exp_f32
    float r = __builtin_amdgcn_rcpf(e + 1.0f);    // v_rcp_f32
    return fmaf(-2.0f, r, 1.0f);
}

__device__ __forceinline__ unsigned pk_u32(fp16x2 v) {
    union { fp16x2 h; unsigned u; } c; c.h = v; return c.u;
}

// (512, 2): 8 waves = 2/EU -> VGPR cap 256; demand ~60 -> no spill.
__launch_bounds__(NTHR, 2)
__global__ void rnn_mfma_kernel(const int* __restrict__ x,
                                const int* __restrict__ xlen,
                                const float* __restrict__ emb,
                                const float* __restrict__ W_ih,
                                const float* __restrict__ W_hh,
                                const float* __restrict__ b_ih,
                                const float* __restrict__ b_hh,
                                const float* __restrict__ W_out,
                                const float* __restrict__ b_out,
                                float* __restrict__ out)
{
    // Barrier-free state exchange: h-fragment kc for lane l at exB[buf][kc][l]
    // (uint4=half8, k = 32kc+8q+j, batch col n = l&15). Wave w writes its uint2
    // in-place (A-row permutation), drains lgkm, then lane0 does ONE LDS
    // atomicAdd(&sCtr,1). Reader of S(t) polls sCtr >= 8*t (uniform broadcast
    // read, monotonic counter).
    //   RAW: writer's data-write precedes its ds_add in the wave's in-order DS
    //   stream (explicit lgkmcnt(0) between); reader's poll-read returning the
    //   target implies the add executed, hence the data-write completed; the
    //   reader's frag reads are issued after (compiler fence) -> see the data.
    //   WAR (2-deep ring): writing S(t+2) over buf[t%2] requires ctr >= 8(t+2)
    //   -> every wave finished step t+1 -> every wave already READ S(t+1)=buf[(t+1)%2]
    //   and S(t)=buf[t%2] (reads drained by that wave's own lgkmcnt(0)). QED.
    //   No deadlock: the wave with the minimum progress always has its poll
    //   target satisfied (all counts >= its own), so the minimum always advances.
    __shared__ __align__(16) uint4 exB[2][4][64];
    __shared__ unsigned sCtr;
    __shared__ __align__(16) float sXW[Vn * XWSTR];   // xw[id][f] = (W_ih.emb[id]+b)*ASCALE
    __shared__ __align__(16) float sHf[ROWS * HFSTR];
    __shared__ __align__(16) unsigned char sXb[ROWS * XBSTR];  // token ids as bytes
    __shared__ float sLogit[ROWS][On];
    __shared__ float sMLS[ROWS];
    __shared__ float sPad[6200];   // 24.8KB pad: total ~81KB -> exactly 1 block/CU

    const int tid  = threadIdx.x;
    const int blk  = blockIdx.x;
    const int row0 = blk * ROWS;

    // volatile touch keeps sPad (and the 1-block/CU LDS footprint) alive
    ((volatile float*)sPad)[tid % 6200] = 0.0f;

    const int w    = tid >> 6;       // wave 0..7 -> owns 16 h features
    const int lane = tid & 63;
    const int n    = lane & 15;      // batch col (B/C) AND A fragment row m
    const int q    = lane >> 4;      // quad
    const int kcW  = w >> 1;         // which 32-k fragment this wave's output feeds
    const int bsel = w & 1;          // which uint2 half of the 16B frag slot

    // ---- A operand (static, 16 VGPRs): PERMUTED row map so C output reg i of
    // lane (q,n) == h feature F = 32*kcW + 8q + 4*bsel + i; the packed tanh
    // output (uint2) is EXACTLY the right 8B of B-fragment kcW -- no cross-lane
    // movement, one ds_write_b64 per lane per step.
    //   A row m = lane&15 loads weight row F(m) = 32*kcW + 8*(m>>2) + 4*bsel + (m&3).
    // Input projection comes from the f32 XW table as accumulator init.
    // Pre-scaled by 2*log2e (tanh input fusion).
    half8 Ah[4];
    const int f = 32 * kcW + 8 * (n >> 2) + 4 * bsel + (n & 3);
    #pragma unroll
    for (int kc = 0; kc < 4; ++kc) {
        const float* p = &W_hh[f * Hn + kc * 32 + q * 8];
        #pragma unroll
        for (int i = 0; i < 8; ++i)
            Ah[kc][i] = (_Float16)(p[i] * ASCALE);
    }

    // ---- xw lookup table (f32, exact): input projection folded to a 57-entry LUT
    for (int idx = tid; idx < Vn * Hn; idx += NTHR) {
        int vo = idx >> 7, ff = idx & 127;
        float acc = b_ih[ff] + b_hh[ff];
        #pragma unroll
        for (int e = 0; e < En; ++e)
            acc = fmaf(emb[vo * En + e], W_ih[ff * En + e], acc);
        sXW[vo * XWSTR + ff] = acc * ASCALE;
    }
    // ---- stage vocab ids as bytes (vocab=57 < 256); int4 load, uchar4 store
    for (int idx = tid * 4; idx < ROWS * Tn; idx += NTHR * 4) {
        int4 v = *(const int4*)&x[row0 * Tn + idx];
        int r = idx >> 9, t = idx & 511;
        uchar4 bb;
        bb.x = (unsigned char)v.x; bb.y = (unsigned char)v.y;
        bb.z = (unsigned char)v.z; bb.w = (unsigned char)v.w;
        *(uchar4*)&sXb[r * XBSTR + t] = bb;
    }
    // ---- zero both exchange buffers (h0 = 0) and the progress counter
    for (int idx = tid; idx < 2 * 4 * 64; idx += NTHR)
        ((uint4*)exB)[idx] = make_uint4(0u, 0u, 0u, 0u);
    if (tid == 0) sCtr = 0u;
    __syncthreads();   // prologue barrier: everything above visible to all waves

    const int Lmax  = xlen[row0];        // sorted descending -> block trip count
    const int len_n = xlen[row0 + n];    // per batch-col freeze point
    const int wOffH = 32 * kcW + 8 * q + 4 * bsel;   // this lane's feature base

    // ---- xw pipeline: prefetched one step ahead (independent of the poll)
    int    idN;
    float4 XWc;
    {
        int id0 = sXb[n * XBSTR];
        XWc = *(const float4*)&sXW[id0 * XWSTR + wOffH];
        idN = sXb[n * XBSTR + (Lmax > 1 ? 1 : 0)];
    }
    float hreg[4] = {0.f, 0.f, 0.f, 0.f};

    // one step, NO barrier: prefetch xw/id for t+1; poll sCtr >= 8t (bounded:
    // a broken protocol fails loudly instead of hanging); fence; 4 uniform
    // b128 frag reads; 4 MFMA depth-2 E/O (aE init = f32 xw); tanh+freeze+pack;
    // uint2 publish; lgkmcnt(0); lane0 ds_add(+1).
    #define RNN_STEP(BR, BW, t)                                                   \
    {                                                                             \
        float4 XWn = *(const float4*)&sXW[idN * XWSTR + wOffH];                   \
        int tn = (t) + 2;                                                         \
        int idN2 = sXb[n * XBSTR + (tn < Lmax ? tn : Lmax - 1)];                  \
        const unsigned tgt = 8u * (unsigned)(t);                                  \
        int spin = 0;                                                             \
        while (((volatile unsigned*)&sCtr)[0] < tgt) {                            \
            if (++spin > (1 << 20)) break;                                        \
        }                                                                         \
        __asm__ __volatile__("" ::: "memory");                                    \
        half8 bf0 = *(const half8*)&exB[BR][0][lane];                             \
        half8 bf1 = *(const half8*)&exB[BR][1][lane];                             \
        half8 bf2 = *(const half8*)&exB[BR][2][lane];                             \
        half8 bf3 = *(const half8*)&exB[BR][3][lane];                             \
        floatx4 aE = {XWc.x, XWc.y, XWc.z, XWc.w};                                \
        floatx4 aO = {0.f, 0.f, 0.f, 0.f};                                        \
        aE = __builtin_amdgcn_mfma_f32_16x16x32_f16(Ah[0], bf0, aE, 0, 0, 0);     \
        aO = __builtin_amdgcn_mfma_f32_16x16x32_f16(Ah[1], bf1, aO, 0, 0, 0);     \
        aE = __builtin_amdgcn_mfma_f32_16x16x32_f16(Ah[2], bf2, aE, 0, 0, 0);     \
        aO = __builtin_amdgcn_mfma_f32_16x16x32_f16(Ah[3], bf3, aO, 0, 0, 0);     \
        const bool upd = ((t) < len_n);                                           \
        _Pragma("unroll")                                                         \
        for (int i = 0; i < 4; ++i) {                                             \
            float v = tanh_scaled(aE[i] + aO[i]);                                 \
            hreg[i] = upd ? v : hreg[i];                                          \
        }                                                                         \
        uint2 pk;                                                                 \
        pk.x = pk_u32(__builtin_amdgcn_cvt_pkrtz(hreg[0], hreg[1]));              \
        pk.y = pk_u32(__builtin_amdgcn_cvt_pkrtz(hreg[2], hreg[3]));              \
        *(uint2*)((_Float16*)&exB[BW][kcW][0] + lane * 8 + 4 * bsel) = pk;        \
        __asm__ __volatile__("s_waitcnt lgkmcnt(0)" ::: "memory");                \
        if (lane == 0) atomicAdd(&sCtr, 1u);                                      \
        XWc = XWn; idN = idN2;                                                    \
    }

    int t = 0;
    for (; t + 2 <= Lmax; t += 2) {
        RNN_STEP(0, 1, t);
        RNN_STEP(1, 0, t + 1);
    }
    if (t < Lmax) {
        RNN_STEP(0, 1, t);
    }
    #undef RNN_STEP

    // ---- publish final fp32 h: lane (q,n) of wave w holds features wOffH+0..3
    {
        float4 f0;
        f0.x = hreg[0]; f0.y = hreg[1]; f0.z = hreg[2]; f0.w = hreg[3];
        *(float4*)&sHf[n * HFSTR + wOffH] = f0;
    }
    __syncthreads();

    // ---- epilogue: logits = relu(h) @ W_out^T + b_out, then log_softmax
    for (int it = tid; it < ROWS * On; it += NTHR) {
        int r = it / On, c = it % On;
        float acc = b_out[c];
        for (int k = 0; k < Hn; ++k) {
            float hv = sHf[r * HFSTR + k];
            hv = hv > 0.0f ? hv : 0.0f;
            acc = fmaf(hv, W_out[c * Hn + k], acc);
        }
        sLogit[r][c] = acc;
    }
    __syncthreads();

    if (tid < ROWS) {
        float m = -INFINITY;
        #pragma unroll
        for (int c = 0; c < On; ++c) m = fmaxf(m, sLogit[tid][c]);
        float s = 0.0f;
        #pragma unroll
        for (int c = 0; c < On; ++c) s += __expf(sLogit[tid][c] - m);
        sMLS[tid] = m + __logf(s);
    }
    __syncthreads();

    for (int it = tid; it < ROWS * On; it += NTHR) {
        int r = it / On, c = it % On;
        out[(row0 + r) * On + c] = sLogit[r][c] - sMLS[r];
    }
}

extern "C" void kernel_launch(void* const* d_in, const int* in_sizes, int n_in,
                              void* d_out, int out_size, void* d_ws, size_t ws_size,
                              hipStream_t stream) {
    const int*   x     = (const int*)d_in[0];
    const int*   xlen  = (const int*)d_in[1];
    const float* emb   = (const float*)d_in[2];
    const float* W_ih  = (const float*)d_in[3];
    const float* W_hh  = (const float*)d_in[4];
    const float* b_ih  = (const float*)d_in[5];
    const float* b_hh  = (const float*)d_in[6];
    const float* W_out = (const float*)d_in[7];
    const float* b_out = (const float*)d_in[8];
    float*       out   = (float*)d_out;

    rnn_mfma_kernel<<<NBLK, NTHR, 0, stream>>>(x, xlen, emb, W_ih, W_hh,
                                               b_ih, b_hh, W_out, b_out, out);
}